// Round 1
// baseline (451.835 us; speedup 1.0000x reference)
//
#include <hip/hip_runtime.h>
#include <hip/hip_bf16.h>

typedef __attribute__((ext_vector_type(8))) short short8;
typedef __attribute__((ext_vector_type(4))) short short4v;
typedef __attribute__((ext_vector_type(4))) float f32x4;

#define NR 8192
#define LOG2E 1.4426950408889634f

__device__ __forceinline__ short f2bf(float f) {
  return __builtin_bit_cast(short, __float2bfloat16(f));
}

// ---------------------------------------------------------------------------
// K1: HT2 = (x @ W)^T in bf16, tiled layout HT2[j>>5][f][j&31] (tile =
// 128x32 bf16 = 8 KB). Fused s,t epilogue (log2e folded). ~10 us. Unchanged.
// ---------------------------------------------------------------------------
__global__ __launch_bounds__(256) void k_gemm_h(const float* __restrict__ x,
                                                const float* __restrict__ W,
                                                const float* __restrict__ a,
                                                short* __restrict__ HT2,
                                                float* __restrict__ sv,
                                                float* __restrict__ tv) {
  __shared__ short WT[128][136];  // pad 8 shorts -> 2-way alias (free, m136)
  const int tid = threadIdx.x;
  const int w = tid >> 6;
  const int L = tid & 63;
  const int lm = L & 15;
  const int q = L >> 4;
  const int i0 = blockIdx.x * 64;

  f32x4 acc[8];
#pragma unroll
  for (int nn = 0; nn < 8; ++nn) acc[nn] = (f32x4){0.f, 0.f, 0.f, 0.f};

  for (int kc = 0; kc < 256; kc += 128) {
    if (kc) __syncthreads();
#pragma unroll
    for (int p = 0; p < 16; ++p) {
      int idx = p * 256 + tid;  // 0..4095
      int k = idx >> 5;         // 0..127
      int f4 = (idx & 31) * 4;
      float4 v = *(const float4*)&W[(kc + k) * 128 + f4];
      WT[f4 + 0][k] = f2bf(v.x);
      WT[f4 + 1][k] = f2bf(v.y);
      WT[f4 + 2][k] = f2bf(v.z);
      WT[f4 + 3][k] = f2bf(v.w);
    }
    __syncthreads();
#pragma unroll
    for (int ks = 0; ks < 4; ++ks) {
      int row = i0 + 16 * w + lm;
      const float* xp = &x[(size_t)row * 256 + kc + ks * 32 + q * 8];
      float4 xa = *(const float4*)xp;
      float4 xb = *(const float4*)(xp + 4);
      short8 af;
      af[0] = f2bf(xa.x); af[1] = f2bf(xa.y); af[2] = f2bf(xa.z); af[3] = f2bf(xa.w);
      af[4] = f2bf(xb.x); af[5] = f2bf(xb.y); af[6] = f2bf(xb.z); af[7] = f2bf(xb.w);
#pragma unroll
      for (int nn = 0; nn < 8; ++nn) {
        short8 bf = *(const short8*)&WT[nn * 16 + lm][ks * 32 + q * 8];
        acc[nn] = __builtin_amdgcn_mfma_f32_16x16x32_bf16(af, bf, acc[nn], 0, 0, 0);
      }
    }
  }

  const int ib = i0 + 16 * w + 4 * q;  // this thread's 4 output j-rows
  const int tbase = (ib >> 5) * 4096 + (ib & 31);
  float a1v[8], a2v[8];
#pragma unroll
  for (int nn = 0; nn < 8; ++nn) {
    a1v[nn] = a[nn * 16 + lm];
    a2v[nn] = a[128 + nn * 16 + lm];
  }
  float sr[4] = {0.f, 0.f, 0.f, 0.f};
  float tr[4] = {0.f, 0.f, 0.f, 0.f};
#pragma unroll
  for (int nn = 0; nn < 8; ++nn) {
    int f = nn * 16 + lm;
    short4v o;
    o[0] = f2bf(acc[nn][0]);
    o[1] = f2bf(acc[nn][1]);
    o[2] = f2bf(acc[nn][2]);
    o[3] = f2bf(acc[nn][3]);
    *(short4v*)&HT2[tbase + f * 32] = o;
#pragma unroll
    for (int r = 0; r < 4; ++r) {
      sr[r] += acc[nn][r] * a1v[nn];
      tr[r] += acc[nn][r] * a2v[nn];
    }
  }
#pragma unroll
  for (int d = 1; d < 16; d <<= 1) {
#pragma unroll
    for (int r = 0; r < 4; ++r) {
      sr[r] += __shfl_xor(sr[r], d);
      tr[r] += __shfl_xor(tr[r], d);
    }
  }
  if (lm == 0) {
#pragma unroll
    for (int r = 0; r < 4; ++r) {
      sv[ib + r] = sr[r] * LOG2E;
      tv[ib + r] = tr[r] * LOG2E;
    }
  }
}

// ---------------------------------------------------------------------------
// K2 (R14): FUSED flash-GAT — no j-split, no part buffer, no k_reduce.
// Block = 512 thr (8 waves) owns 16 i-rows x FULL j-range; wave w sweeps
// j-tiles [w*32, w*32+32). Grid = 8192/16 = 512 blocks = exactly 2/CU
// (64 KB LDS) = 16 waves/CU — same occupancy as R13, but:
//   * HT2 (2 MB, L2-resident) read DIRECTLY into MFMA B-fragments
//     (short8 global loads, 1 KB/wave contiguous per fragment) — the LDS
//     staging + XOR swizzle + per-8-tile barriers were overhead for an
//     L2-resident operand. Main loop now has ZERO barriers -> compiler
//     software-pipelines tiles freely.
//   * adj prefetched 1 tile ahead (proven R13 pattern; 4 waves/SIMD TLP
//     covers the ~900cy HBM latency).
//   * epilogue: cross-wave reduction via the 64 KB LDS buffer
//     (l-scratch pass, then acc pass), final division in-kernel, direct
//     coalesced float4 out store. Saves 64 MB part write + 64 MB read +
//     the k_reduce dispatch.
// ---------------------------------------------------------------------------
__global__ __launch_bounds__(512, 4) void k_flash(const int* __restrict__ adj,
                                                  const short* __restrict__ HT2,
                                                  const float* __restrict__ sv,
                                                  const float* __restrict__ tv,
                                                  float* __restrict__ out) {
  __shared__ float red[8][16][128];  // 64 KB; reused as l-scratch first
  const int tid = threadIdx.x;
  const int w = tid >> 6;   // 0..7
  const int L = tid & 63;
  const int lm = L & 15;
  const int q = L >> 4;
  const int i0 = blockIdx.x * 16;
  const int row = i0 + lm;         // A-fragment row for this lane
  const float s0 = sv[row];
  const size_t ar = (size_t)row * NR;

  f32x4 acc[8];
#pragma unroll
  for (int nn = 0; nn < 8; ++nn) acc[nn] = (f32x4){0.f, 0.f, 0.f, 0.f};
  float l0 = 0.f;

  const int t0 = w * 32;  // this wave's 32 j-tiles
  // prologue: stage tile t0's adj (the only HBM stream in the loop)
  int jb = t0 * 32 + q * 8;
  int4 sa0 = *(const int4*)&adj[ar + jb];
  int4 sa1 = *(const int4*)&adj[ar + jb + 4];

  for (int t = t0; t < t0 + 32; ++t) {
    int4 a0 = sa0, a1 = sa1;
    if (t + 1 < t0 + 32) {
      int jn = (t + 1) * 32 + q * 8;
      sa0 = *(const int4*)&adj[ar + jn];
      sa1 = *(const int4*)&adj[ar + jn + 4];
    }
    const int jc = t * 32 + q * 8;
    float4 tva = *(const float4*)&tv[jc];
    float4 tvb = *(const float4*)&tv[jc + 4];
    // B-fragments straight from L2: same indexing the old LDS path consumed
    const short* hp = &HT2[(size_t)t * 4096 + lm * 32 + q * 8];
    short8 bf[8];
#pragma unroll
    for (int nn = 0; nn < 8; ++nn) bf[nn] = *(const short8*)&hp[nn * 512];

    int av[8] = {a0.x, a0.y, a0.z, a0.w, a1.x, a1.y, a1.z, a1.w};
    float tvl[8] = {tva.x, tva.y, tva.z, tva.w, tvb.x, tvb.y, tvb.z, tvb.w};
    short8 p0;
#pragma unroll
    for (int e = 0; e < 8; ++e) {
      // logits pre-scaled by log2e; lrelu(v) = max(v, 0.2v) commutes w/ scale
      float v0 = s0 + tvl[e];
      float e0 = fmaxf(v0, 0.2f * v0);
      float pp = (av[e] > 0) ? __builtin_amdgcn_exp2f(e0) : 0.f;
      l0 += pp;
      p0[e] = f2bf(pp);
    }
#pragma unroll
    for (int nn = 0; nn < 8; ++nn)
      acc[nn] = __builtin_amdgcn_mfma_f32_16x16x32_bf16(p0, bf[nn], acc[nn], 0, 0, 0);
  }

  // ---- cross-wave reduction (3 barriers, epilogue only) ----
  float* scratch = &red[0][0][0];
  // denominator: fold the 4 q-replicas, then across the 8 waves via LDS
  l0 += __shfl_xor(l0, 16);
  l0 += __shfl_xor(l0, 32);
  if (L < 16) scratch[w * 16 + lm] = l0;  // q==0 lanes: one per row
  __syncthreads();
  const int idx = tid * 4;  // this thread's out chunk: row r_, cols f_..f_+3
  const int r_ = idx >> 7;
  const int f_ = idx & 127;
  float lsum = 0.f;
#pragma unroll
  for (int ww = 0; ww < 8; ++ww) lsum += scratch[ww * 16 + r_];
  __syncthreads();  // l-scratch read done before acc overwrites it
#pragma unroll
  for (int nn = 0; nn < 8; ++nn)
#pragma unroll
    for (int r = 0; r < 4; ++r)
      red[w][4 * q + r][nn * 16 + lm] = acc[nn][r];
  __syncthreads();
  f32x4 sum = (f32x4){0.f, 0.f, 0.f, 0.f};
#pragma unroll
  for (int ww = 0; ww < 8; ++ww) {
    const f32x4 v = *(const f32x4*)&red[ww][r_][f_];
    sum[0] += v[0]; sum[1] += v[1]; sum[2] += v[2]; sum[3] += v[3];
  }
  float inv = (lsum > 0.f) ? 1.f / lsum : 0.f;
  f32x4 o;
  o[0] = sum[0] * inv; o[1] = sum[1] * inv; o[2] = sum[2] * inv; o[3] = sum[3] * inv;
  *(f32x4*)&out[(size_t)(i0 + r_) * 128 + f_] = o;
}

extern "C" void kernel_launch(void* const* d_in, const int* in_sizes, int n_in,
                              void* d_out, int out_size, void* d_ws, size_t ws_size,
                              hipStream_t stream) {
  const float* x = (const float*)d_in[0];    // 8192 x 256 fp32
  const int* adj = (const int*)d_in[1];      // 8192 x 8192 int32
  const float* W = (const float*)d_in[2];    // 256 x 128 fp32
  const float* a = (const float*)d_in[3];    // 256 x 1 fp32
  float* out = (float*)d_out;                // 8192 x 128 fp32

  char* ws = (char*)d_ws;
  short* HT2 = (short*)(ws + 0);          // 2 MB  bf16 h tiled [256][128][32]
  float* sv = (float*)(ws + 2097152);     // 32 KB (pre-scaled by log2e)
  float* tv = (float*)(ws + 2129920);     // 32 KB

  hipLaunchKernelGGL(k_gemm_h, dim3(128), dim3(256), 0, stream, x, W, a, HT2, sv, tv);
  hipLaunchKernelGGL(k_flash, dim3(512), dim3(512), 0, stream, adj, HT2, sv, tv, out);
}

// Round 2
// 431.880 us; speedup vs baseline: 1.0462x; 1.0462x over previous
//
#include <hip/hip_runtime.h>
#include <hip/hip_bf16.h>

typedef __attribute__((ext_vector_type(8))) short short8;
typedef __attribute__((ext_vector_type(4))) short short4v;
typedef __attribute__((ext_vector_type(4))) float f32x4;

#define NR 8192
#define LOG2E 1.4426950408889634f

__device__ __forceinline__ short f2bf(float f) {
  return __builtin_bit_cast(short, __float2bfloat16(f));
}

// ---------------------------------------------------------------------------
// K1: HT2 = (x @ W)^T in bf16, tiled layout HT2[j>>5][f][j&31] (tile =
// 128x32 bf16 = 8 KB). Fused s,t epilogue (log2e folded). ~10 us.
// ---------------------------------------------------------------------------
__global__ __launch_bounds__(256) void k_gemm_h(const float* __restrict__ x,
                                                const float* __restrict__ W,
                                                const float* __restrict__ a,
                                                short* __restrict__ HT2,
                                                float* __restrict__ sv,
                                                float* __restrict__ tv) {
  __shared__ short WT[128][136];  // pad 8 shorts -> 2-way alias (free, m136)
  const int tid = threadIdx.x;
  const int w = tid >> 6;
  const int L = tid & 63;
  const int lm = L & 15;
  const int q = L >> 4;
  const int i0 = blockIdx.x * 64;

  f32x4 acc[8];
#pragma unroll
  for (int nn = 0; nn < 8; ++nn) acc[nn] = (f32x4){0.f, 0.f, 0.f, 0.f};

  for (int kc = 0; kc < 256; kc += 128) {
    if (kc) __syncthreads();
#pragma unroll
    for (int p = 0; p < 16; ++p) {
      int idx = p * 256 + tid;  // 0..4095
      int k = idx >> 5;         // 0..127
      int f4 = (idx & 31) * 4;
      float4 v = *(const float4*)&W[(kc + k) * 128 + f4];
      WT[f4 + 0][k] = f2bf(v.x);
      WT[f4 + 1][k] = f2bf(v.y);
      WT[f4 + 2][k] = f2bf(v.z);
      WT[f4 + 3][k] = f2bf(v.w);
    }
    __syncthreads();
#pragma unroll
    for (int ks = 0; ks < 4; ++ks) {
      int row = i0 + 16 * w + lm;
      const float* xp = &x[(size_t)row * 256 + kc + ks * 32 + q * 8];
      float4 xa = *(const float4*)xp;
      float4 xb = *(const float4*)(xp + 4);
      short8 af;
      af[0] = f2bf(xa.x); af[1] = f2bf(xa.y); af[2] = f2bf(xa.z); af[3] = f2bf(xa.w);
      af[4] = f2bf(xb.x); af[5] = f2bf(xb.y); af[6] = f2bf(xb.z); af[7] = f2bf(xb.w);
#pragma unroll
      for (int nn = 0; nn < 8; ++nn) {
        short8 bf = *(const short8*)&WT[nn * 16 + lm][ks * 32 + q * 8];
        acc[nn] = __builtin_amdgcn_mfma_f32_16x16x32_bf16(af, bf, acc[nn], 0, 0, 0);
      }
    }
  }

  const int ib = i0 + 16 * w + 4 * q;  // this thread's 4 output j-rows
  const int tbase = (ib >> 5) * 4096 + (ib & 31);
  float a1v[8], a2v[8];
#pragma unroll
  for (int nn = 0; nn < 8; ++nn) {
    a1v[nn] = a[nn * 16 + lm];
    a2v[nn] = a[128 + nn * 16 + lm];
  }
  float sr[4] = {0.f, 0.f, 0.f, 0.f};
  float tr[4] = {0.f, 0.f, 0.f, 0.f};
#pragma unroll
  for (int nn = 0; nn < 8; ++nn) {
    int f = nn * 16 + lm;
    short4v o;
    o[0] = f2bf(acc[nn][0]);
    o[1] = f2bf(acc[nn][1]);
    o[2] = f2bf(acc[nn][2]);
    o[3] = f2bf(acc[nn][3]);
    *(short4v*)&HT2[tbase + f * 32] = o;
#pragma unroll
    for (int r = 0; r < 4; ++r) {
      sr[r] += acc[nn][r] * a1v[nn];
      tr[r] += acc[nn][r] * a2v[nn];
    }
  }
#pragma unroll
  for (int d = 1; d < 16; d <<= 1) {
#pragma unroll
    for (int r = 0; r < 4; ++r) {
      sr[r] += __shfl_xor(sr[r], d);
      tr[r] += __shfl_xor(tr[r], d);
    }
  }
  if (lm == 0) {
#pragma unroll
    for (int r = 0; r < 4; ++r) {
      sv[ib + r] = sr[r] * LOG2E;
      tv[ib + r] = tr[r] * LOG2E;
    }
  }
}

// ---------------------------------------------------------------------------
// K3 (R15): round-0's LDS-resident flash structure RESTORED (the LDS tile
// staging shares each HT2 tile across 8 waves — it is the traffic-sharing
// mechanism, not overhead: R14's direct-L2 fusion ran 1.3 GB through the
// CUs' ~10-13 B/cy/CU load pipes = 167 us), with S halved 16 -> 8:
//   * part traffic 64+64 MB -> 32+32 MB, lpart halved
//   * grid 1024 -> 512 blocks = exactly 2/CU, single residency round
//   * per-wave 32 tiles in 4 stage-phases of 8 tiles (same per-phase cost)
// Traffic model: adj 256 + HT2 128 + part 32 + eps ~= 416 MB @ ~8 TB/s
// line-rate => ~55 us.
// ---------------------------------------------------------------------------
__global__ __launch_bounds__(512, 4) void k_flash(const int* __restrict__ adj,
                                                  const short* __restrict__ HT2,
                                                  const float* __restrict__ sv,
                                                  const float* __restrict__ tv,
                                                  float* __restrict__ part,
                                                  float* __restrict__ lpart) {
  __shared__ short lds_s[32768];  // 64 KB: 8 tiles x 8 KB, swizzled
  unsigned* ldsw = (unsigned*)lds_s;
  const int tid = threadIdx.x;
  const int w = tid >> 6;   // 0..7
  const int L = tid & 63;
  const int lm = L & 15;
  const int q = L >> 4;
  const int sp = blockIdx.x & 7;   // j-split (S=8)
  const int it = blockIdx.x >> 3;  // i-tile (64 x 128 rows)
  const int i0 = it * 128;

  const int row0 = i0 + 16 * w + lm;  // each wave: 16 rows
  const float s0 = sv[row0];
  const size_t ar0 = (size_t)row0 * NR;

  f32x4 acc[8];
#pragma unroll
  for (int nn = 0; nn < 8; ++nn) acc[nn] = (f32x4){0.f, 0.f, 0.f, 0.f};
  float l0 = 0.f;

  const int tile0 = sp * 32;  // 32 tiles per split
  // prologue: stage tile0's adj (the only HBM stream in the loop)
  int jb = tile0 * 32 + q * 8;
  int4 sa00 = *(const int4*)&adj[ar0 + jb];
  int4 sa01 = *(const int4*)&adj[ar0 + jb + 4];

  for (int t = 0; t < 32; ++t) {
    if ((t & 7) == 0) {  // stage phase t>>3: 8 tiles -> 64 KB LDS (swizzled)
      __syncthreads();   // prior phase's readers done
      const int pbase_t = tile0 + t;
#pragma unroll
      for (int z = 0; z < 8; ++z) {
        int id = z * 512 + tid;  // 0..4095 uint4s
        int tt = id >> 9;        // tile in phase
        int k = id & 511;
        int f = k >> 2, c = k & 3;
        uint4 v = *(const uint4*)&HT2[(size_t)(pbase_t + tt) * 4096 + k * 8];
        int cs = c ^ ((f >> 1) & 3);
        *(uint4*)&ldsw[tt * 2048 + f * 16 + cs * 4] = v;
      }
      __syncthreads();
    }
    // consume staged adj; prefetch next tile's adj
    int4 a00 = sa00, a01 = sa01;
    if (t + 1 < 32) {
      int jn = (tile0 + t + 1) * 32 + q * 8;
      sa00 = *(const int4*)&adj[ar0 + jn];
      sa01 = *(const int4*)&adj[ar0 + jn + 4];
    }
    const int jc = (tile0 + t) * 32 + q * 8;
    float4 tv0 = *(const float4*)&tv[jc];
    float4 tv1 = *(const float4*)&tv[jc + 4];
    const int tt = t & 7;
    short8 bf[8];
#pragma unroll
    for (int nn = 0; nn < 8; ++nn) {
      int f = nn * 16 + lm;
      bf[nn] = *(const short8*)&ldsw[tt * 2048 + f * 16 + ((q ^ ((f >> 1) & 3)) * 4)];
    }

    int av0[8] = {a00.x, a00.y, a00.z, a00.w, a01.x, a01.y, a01.z, a01.w};
    float tvl[8] = {tv0.x, tv0.y, tv0.z, tv0.w, tv1.x, tv1.y, tv1.z, tv1.w};
    short8 p0;
#pragma unroll
    for (int e = 0; e < 8; ++e) {
      // logits pre-scaled by log2e; lrelu(v) = max(v, 0.2v)
      float v0 = s0 + tvl[e];
      float e0 = fmaxf(v0, 0.2f * v0);
      float pp0 = (av0[e] > 0) ? __builtin_amdgcn_exp2f(e0) : 0.f;
      l0 += pp0;
      p0[e] = f2bf(pp0);
    }
#pragma unroll
    for (int nn = 0; nn < 8; ++nn)
      acc[nn] = __builtin_amdgcn_mfma_f32_16x16x32_bf16(p0, bf[nn], acc[nn], 0, 0, 0);
  }
  __syncthreads();  // slice LDS free -> reuse for epilogue

  // epilogue: wave-private LDS transpose (8 KB/wave = 64 KB), contiguous
  // float4 stores. Single-wave region: lgkmcnt orders, no barrier.
  float* my = (float*)lds_s + w * 2048;
#pragma unroll
  for (int nn = 0; nn < 8; ++nn)
#pragma unroll
    for (int r = 0; r < 4; ++r)
      my[(4 * q + r) * 128 + nn * 16 + lm] = acc[nn][r];
  float* pbase = part + ((size_t)sp * NR + i0 + 16 * w) * 128;
#pragma unroll
  for (int c = 0; c < 8; ++c) {
    int idx = (c * 64 + L) * 4;
    *(float4*)&pbase[idx] = *(const float4*)&my[idx];
  }

  // denominator: reduce the 4 q-replicas of each row
  l0 += __shfl_xor(l0, 16);
  l0 += __shfl_xor(l0, 32);
  if (q == 0) lpart[sp * NR + row0] = l0;
}

// ---------------------------------------------------------------------------
// K4: out[i][f] = sum_sp part / sum_sp lpart   (float4 vectorized)
// ---------------------------------------------------------------------------
__global__ __launch_bounds__(256) void k_reduce(const float* __restrict__ part,
                                                const float* __restrict__ lpart,
                                                float* __restrict__ out, int S) {
  int idx4 = blockIdx.x * 256 + threadIdx.x;
  int idx = idx4 * 4;  // i*128+f
  int i = idx >> 7;
  float4 sum = {0.f, 0.f, 0.f, 0.f};
  for (int sp = 0; sp < S; ++sp) {
    float4 v = *(const float4*)&part[(size_t)sp * (NR * 128) + idx];
    sum.x += v.x; sum.y += v.y; sum.z += v.z; sum.w += v.w;
  }
  float l = 0.f;
  for (int sp = 0; sp < S; ++sp) l += lpart[sp * NR + i];
  float inv = (l > 0.f) ? 1.f / l : 0.f;
  float4 o = {sum.x * inv, sum.y * inv, sum.z * inv, sum.w * inv};
  *(float4*)&out[idx] = o;
}

extern "C" void kernel_launch(void* const* d_in, const int* in_sizes, int n_in,
                              void* d_out, int out_size, void* d_ws, size_t ws_size,
                              hipStream_t stream) {
  const float* x = (const float*)d_in[0];    // 8192 x 256 fp32
  const int* adj = (const int*)d_in[1];      // 8192 x 8192 int32
  const float* W = (const float*)d_in[2];    // 256 x 128 fp32
  const float* a = (const float*)d_in[3];    // 256 x 1 fp32
  float* out = (float*)d_out;                // 8192 x 128 fp32

  char* ws = (char*)d_ws;
  short* HT2 = (short*)(ws + 0);          // 2 MB  bf16 h tiled [256][128][32]
  float* sv = (float*)(ws + 2097152);     // 32 KB (pre-scaled by log2e)
  float* tv = (float*)(ws + 2129920);     // 32 KB
  float* lpart = (float*)(ws + 2162688);  // 8*32 KB = 256 KB
  float* part = (float*)(ws + 2424832);   // 8 * 4 MB = 32 MB

  const int S = 8;  // j-splits: 64 i-tiles x 8 = 512 blocks of 8 waves

  hipLaunchKernelGGL(k_gemm_h, dim3(128), dim3(256), 0, stream, x, W, a, HT2, sv, tv);
  hipLaunchKernelGGL(k_flash, dim3(64 * S), dim3(512), 0, stream, adj, HT2, sv, tv,
                     part, lpart);
  hipLaunchKernelGGL(k_reduce, dim3((NR * 128) / 1024), dim3(256), 0, stream, part,
                     lpart, out, S);
}